// Round 6
// baseline (60.154 us; speedup 1.0000x reference)
//
#include <hip/hip_runtime.h>
#include <hip/hip_bf16.h>

// PNN forward, round 6: uniform-phase 256x256 pipeline on mfma 32x32x16.
// Root cause of r3-r5's flat ~1900cyc/phase: my lgkmcnt(0)-after-barrier
// forced THIS phase's LDS reads to drain before THIS phase's MFMA (all waves
// lockstep) -> reads and MFMA serialized. Fix: counted lgkmcnt(6) - phase p
// issues 6 reads for p+1, waits only for p-1's reads, so the LDS drain runs
// under the MFMA window. 32x32x16 shape makes phases uniform (no Q0 burst)
// and fits the double-banked fragment regs in the 256-reg budget.
// bf16 exact: d2 ~ 1365 >> 210 (f32 exp underflow) -> probs are 0.0f in both
// reference and kernel regardless of bf16 rounding.

typedef __attribute__((ext_vector_type(4))) float f32x4;
typedef __attribute__((ext_vector_type(16))) float f32x16;
typedef __attribute__((ext_vector_type(8))) short bf16x8;
typedef __attribute__((ext_vector_type(4))) unsigned short u16x4;

typedef __attribute__((address_space(3))) unsigned lds_u;
typedef __attribute__((address_space(1))) unsigned glb_u;

constexpr int Mdim = 4096;   // batch
constexpr int Ndim = 4096;   // OUT*ND
constexpr int Kdim = 1024;   // IN
constexpr int OUTC = 512;

// Workspace layout (bytes)
constexpr size_t WS_XB = 0;
constexpr size_t WS_CB = (size_t)Mdim * Kdim * 2;
constexpr size_t WS_X2 = WS_CB + (size_t)Ndim * Kdim * 2;
constexpr size_t WS_C2 = WS_X2 + (size_t)Mdim * 4;
constexpr size_t WS_NEED = WS_C2 + (size_t)Ndim * 4;

__device__ __forceinline__ unsigned short f2bf(float f) {
  return __bfloat16_as_ushort(__float2bfloat16(f));
}

// ---------------- Kernel 1: f32 -> bf16 + squared norms --------------------
__global__ __launch_bounds__(256) void convert_norm(
    const float* __restrict__ X, const float* __restrict__ Cc,
    ushort* __restrict__ Xb, ushort* __restrict__ Cb,
    float* __restrict__ x2, float* __restrict__ c2) {
  const int lane = threadIdx.x & 63;
  const int row  = blockIdx.x * 4 + (threadIdx.x >> 6);   // 0..8191
  const bool isX = row < Mdim;
  const float* src = isX ? X + (size_t)row * Kdim : Cc + (size_t)(row - Mdim) * Kdim;
  ushort* dst      = isX ? Xb + (size_t)row * Kdim : Cb + (size_t)(row - Mdim) * Kdim;
  float s = 0.f;
#pragma unroll
  for (int p = 0; p < 4; ++p) {
    f32x4 v = *(const f32x4*)(src + p * 256 + lane * 4);
    s = fmaf(v[0], v[0], fmaf(v[1], v[1], fmaf(v[2], v[2], fmaf(v[3], v[3], s))));
    u16x4 b = {f2bf(v[0]), f2bf(v[1]), f2bf(v[2]), f2bf(v[3])};
    *(u16x4*)(dst + p * 256 + lane * 4) = b;
  }
#pragma unroll
  for (int sh = 1; sh < 64; sh <<= 1) s += __shfl_xor(s, sh);
  if (lane == 0) { if (isX) x2[row] = s; else c2[row - Mdim] = s; }
}

// ---------------- Kernel 2: uniform-phase 32x32x16 GEMM --------------------
#define VM0() asm volatile("s_waitcnt vmcnt(0)" ::: "memory")
#define LG6  asm volatile("s_waitcnt lgkmcnt(6)" ::: "memory")
#define LG0  asm volatile("s_waitcnt lgkmcnt(0)" ::: "memory")
#define BAR() __builtin_amdgcn_s_barrier()
#define SB0  __builtin_amdgcn_sched_barrier(0)
#define PRIO1 __builtin_amdgcn_s_setprio(1)
#define PRIO0 __builtin_amdgcn_s_setprio(0)

// Stage a full 256x64 tile matrix-half (4 x global_load_lds w=16 per thread).
// LDS dest linear (tid*16B + i*8KiB); T2 swizzle folded into the per-lane
// GLOBAL source chunk (rule 21): LDS slot s of row r holds chunk s ^ (r&7).
#define STAGE_A4(P, T)                                                            \
  { const ushort* g = Xb + (size_t)(bm0 + srow) * Kdim + (T) * 64 + schunk * 8;   \
    ushort* l = smemA + (P) * 16384 + tid * 8;                                    \
    __builtin_amdgcn_global_load_lds((const glb_u*)g, (lds_u*)l, 16, 0, 0);       \
    __builtin_amdgcn_global_load_lds((const glb_u*)(g + (size_t)64  * Kdim),      \
                                     (lds_u*)(l + 4096), 16, 0, 0);               \
    __builtin_amdgcn_global_load_lds((const glb_u*)(g + (size_t)128 * Kdim),      \
                                     (lds_u*)(l + 8192), 16, 0, 0);               \
    __builtin_amdgcn_global_load_lds((const glb_u*)(g + (size_t)192 * Kdim),      \
                                     (lds_u*)(l + 12288), 16, 0, 0); }

#define STAGE_B4(P, T)                                                            \
  { const ushort* g = Cb + (size_t)(bn0 + srow) * Kdim + (T) * 64 + schunk * 8;   \
    ushort* l = smemB + (P) * 16384 + tid * 8;                                    \
    __builtin_amdgcn_global_load_lds((const glb_u*)g, (lds_u*)l, 16, 0, 0);       \
    __builtin_amdgcn_global_load_lds((const glb_u*)(g + (size_t)64  * Kdim),      \
                                     (lds_u*)(l + 4096), 16, 0, 0);               \
    __builtin_amdgcn_global_load_lds((const glb_u*)(g + (size_t)128 * Kdim),      \
                                     (lds_u*)(l + 8192), 16, 0, 0);               \
    __builtin_amdgcn_global_load_lds((const glb_u*)(g + (size_t)192 * Kdim),      \
                                     (lds_u*)(l + 12288), 16, 0, 0); }

// Opaque ds_read: no compiler-visible dep on gload_lds; ordering carried by
// the explicit lgkm/vm schedule.
#define DSR(dst, a) asm volatile("ds_read_b128 %0, %1" : "=v"(dst) : "v"(a))

// 6 fragment reads (4 A-frags + 2 B-frags) at k-step KK of buffer BOFF into
// register bank RA/RB. Feeds NEXT phase's MFMA.
#define RD6(RA, RB, BOFF, KK)                                                     \
  DSR(RA[0], aB0 + (BOFF) + off##KK);                                             \
  DSR(RA[1], aB1 + (BOFF) + off##KK);                                             \
  DSR(RA[2], aB2 + (BOFF) + off##KK);                                             \
  DSR(RA[3], aB3 + (BOFF) + off##KK);                                             \
  DSR(RB[0], bB0 + (BOFF) + off##KK);                                             \
  DSR(RB[1], bB1 + (BOFF) + off##KK);

#define MF(a, b, c) __builtin_amdgcn_mfma_f32_32x32x16_bf16(a, b, c, 0, 0, 0)
#define MFMA8(RA, RB)                                                             \
  acc[0][0] = MF(RA[0], RB[0], acc[0][0]); acc[1][0] = MF(RA[1], RB[0], acc[1][0]);\
  acc[2][0] = MF(RA[2], RB[0], acc[2][0]); acc[3][0] = MF(RA[3], RB[0], acc[3][0]);\
  acc[0][1] = MF(RA[0], RB[1], acc[0][1]); acc[1][1] = MF(RA[1], RB[1], acc[1][1]);\
  acc[2][1] = MF(RA[2], RB[1], acc[2][1]); acc[3][1] = MF(RA[3], RB[1], acc[3][1]);

// One K-tile = 4 uniform phases. Phase: [stage?/VM? ; BAR ; 6 reads(k+1) ;
// lgkmcnt(6) (= wait k's reads, keep k+1's in flight) ; 8 MFMA(k)].
// WAR: stage@(t,1) vs last read of that buf @(t-1,2) = +3 phases, one-barrier
// safe (reader's lgkm@(t-1,3) precedes its arrival at BAR@(t,0) which gates
// the stager's issue@(t,1)). RAW: VM0@(t,3) + BAR before reads of tile t+1.
#define TILE(BOFF, T)                                                             \
  BAR(); RD6(R0A, R0B, (BOFF), 1); LG6; SB0; PRIO1; MFMA8(R1A, R1B); PRIO0;       \
  STAGE_A4(((BOFF) ^ 32768) >> 15, (T) + 1);                                      \
  BAR(); RD6(R1A, R1B, (BOFF), 2); LG6; SB0; PRIO1; MFMA8(R0A, R0B); PRIO0;       \
  STAGE_B4(((BOFF) ^ 32768) >> 15, (T) + 1);                                      \
  BAR(); RD6(R0A, R0B, (BOFF), 3); LG6; SB0; PRIO1; MFMA8(R1A, R1B); PRIO0;       \
  VM0();                                                                          \
  BAR(); RD6(R1A, R1B, (BOFF) ^ 32768, 0); LG6; SB0; PRIO1; MFMA8(R0A, R0B); PRIO0;

__global__ __launch_bounds__(512, 2) void pnn_gemm8(
    const ushort* __restrict__ Xb, const ushort* __restrict__ Cb,
    const float* __restrict__ x2g, const float* __restrict__ c2g,
    float* __restrict__ Out) {
  extern __shared__ ushort smem[];
  ushort* smemA = smem;            // [2 buf][256 rows][64 k] bf16 = 64 KiB
  ushort* smemB = smem + 32768;    // same, at byte 65536

  const int tid  = threadIdx.x;
  const int lane = tid & 63;
  const int wid  = tid >> 6;       // 0..7
  const int wm   = wid >> 2;       // 0..1 -> 128-row half
  const int wn   = wid & 3;        // 0..3 -> 64-col slice

  // XCD-aware swizzle (T1): XCD k gets a 4x8 tile rectangle (FETCH 37->26MB).
  const int L    = blockIdx.x;         // 0..255
  const int xcd  = L & 7, slot = L >> 3;
  const int by   = (xcd >> 1) * 4 + (slot >> 3);
  const int bx   = (xcd & 1) * 8 + (slot & 7);
  const int bm0  = by * 256;
  const int bn0  = bx * 256;

  // Staging: thread covers rows srow+{0,64,128,192}; source chunk pre-swizzled.
  const int srow   = tid >> 3;                 // 0..63
  const int schunk = (tid & 7) ^ (srow & 7);

  // Fragment-read addresses. 32x32x16 A/B operand: row/col = lane&31,
  // k = (lane>>5)*8 + e. Logical 16B chunk = kk*2 + (lane>>5); physical =
  // logical ^ (row&7), row&7 == lane&7.
  const int l31 = lane & 31, lh5 = lane >> 5, lx7 = lane & 7;
  const unsigned ldsA = (unsigned)(uintptr_t)(lds_u*)smem;
  const unsigned off0 = (unsigned)(((0 | lh5) ^ lx7) << 4);
  const unsigned off1 = (unsigned)(((2 | lh5) ^ lx7) << 4);
  const unsigned off2 = (unsigned)(((4 | lh5) ^ lx7) << 4);
  const unsigned off3 = (unsigned)(((6 | lh5) ^ lx7) << 4);
  const unsigned aB0 = ldsA + (unsigned)((wm * 128 + 0  + l31) * 128);
  const unsigned aB1 = ldsA + (unsigned)((wm * 128 + 32 + l31) * 128);
  const unsigned aB2 = ldsA + (unsigned)((wm * 128 + 64 + l31) * 128);
  const unsigned aB3 = ldsA + (unsigned)((wm * 128 + 96 + l31) * 128);
  const unsigned bB0 = ldsA + 65536u + (unsigned)((wn * 64 + 0  + l31) * 128);
  const unsigned bB1 = ldsA + 65536u + (unsigned)((wn * 64 + 32 + l31) * 128);

  f32x16 acc[4][2];
#pragma unroll
  for (int i = 0; i < 4; ++i)
#pragma unroll
    for (int j = 0; j < 2; ++j)
#pragma unroll
      for (int e = 0; e < 16; ++e) acc[i][j][e] = 0.f;
  bf16x8 R0A[4], R0B[2], R1A[4], R1B[2];   // phase-parity register banks

  // Prologue: tile0 (A+B, 8 loads), drain, first reads (kk0 -> bank R1).
  STAGE_A4(0, 0);
  STAGE_B4(0, 0);
  VM0();
  BAR();
  RD6(R1A, R1B, 0, 0);

  // 16 K-tiles; loop does pairs to keep buffer parity static.
#pragma unroll 1
  for (int i = 0; i < 7; ++i) {
    const int t0 = 2 * i;
    TILE(0, t0);           // tile t0   (buf0), stages t0+1 into buf1
    TILE(32768, t0 + 1);   // tile t0+1 (buf1), stages t0+2 into buf0
  }
  TILE(0, 14);             // tile 14 (buf0), stages tile 15, reads (15,kk0)
  // Tile 15 (buf1): no stages, barriers unnecessary (no LDS writes remain).
  RD6(R0A, R0B, 32768, 1); LG6; SB0; PRIO1; MFMA8(R1A, R1B); PRIO0;
  RD6(R1A, R1B, 32768, 2); LG6; SB0; PRIO1; MFMA8(R0A, R0B); PRIO0;
  RD6(R0A, R0B, 32768, 3); LG6; SB0; PRIO1; MFMA8(R1A, R1B); PRIO0;
  LG0; SB0; PRIO1; MFMA8(R0A, R0B); PRIO0;

  // Epilogue: d2 = x2 + c2 - 2S; p = exp(-d2/2); max&sum over 8 N-cols
  // (lanes l^{1,2,4}); out = (9*max - sum)/8.
  // 32x32 C/D layout (m74/m101): col = lane&31,
  // row = (reg&3) + 8*(reg>>2) + 4*(lane>>5).
#pragma unroll
  for (int mi = 0; mi < 4; ++mi) {
    const int rbase = bm0 + wm * 128 + mi * 32 + 4 * lh5;
#pragma unroll
    for (int ni = 0; ni < 2; ++ni) {
      const int cL = bn0 + wn * 64 + ni * 32 + l31;
      const float cv = c2g[cL];
      f32x16 a = acc[mi][ni];
      float pm[16], ps[16];
#pragma unroll
      for (int j = 0; j < 16; ++j) {
        const int rL = rbase + (j & 3) + 8 * (j >> 2);
        const float d = x2g[rL] + cv - 2.f * a[j];
        pm[j] = __expf(-0.5f * d);
        ps[j] = pm[j];
      }
#pragma unroll
      for (int s = 1; s < 8; s <<= 1) {
#pragma unroll
        for (int j = 0; j < 16; ++j) {
          pm[j] = fmaxf(pm[j], __shfl_xor(pm[j], s));
          ps[j] += __shfl_xor(ps[j], s);
        }
      }
      if ((lane & 7) == 0) {
        const int o = cL >> 3;
#pragma unroll
        for (int j = 0; j < 16; ++j) {
          const int rL = rbase + (j & 3) + 8 * (j >> 2);
          Out[(size_t)rL * OUTC + o] = (pm[j] * 9.f - ps[j]) * 0.125f;
        }
      }
    }
  }
}

// ---------------- Fallback: fused single-kernel (no workspace) -------------
__device__ inline unsigned long long pack4(f32x4 v) {
  return (unsigned long long)f2bf(v[0]) | ((unsigned long long)f2bf(v[1]) << 16) |
         ((unsigned long long)f2bf(v[2]) << 32) | ((unsigned long long)f2bf(v[3]) << 48);
}

__global__ __launch_bounds__(256) void pnn_fused(const float* __restrict__ X,
                                                 const float* __restrict__ Cc,
                                                 float* __restrict__ Out) {
  __shared__ alignas(16) unsigned long long As[128 * 16];
  __shared__ alignas(16) unsigned long long Bs[128 * 16];
  __shared__ float x2s[128];
  __shared__ float c2s[128];

  const int tid = threadIdx.x, lane = tid & 63, wid = tid >> 6;
  const int bm0 = blockIdx.y * 128, bn0 = blockIdx.x * 128;
  const int wm = (wid >> 1) * 64, wn = (wid & 1) * 64;

  f32x4 acc[4][4];
#pragma unroll
  for (int i = 0; i < 4; ++i)
#pragma unroll
    for (int j = 0; j < 4; ++j) acc[i][j] = f32x4{0.f, 0.f, 0.f, 0.f};
  float sqa[8], sqb[8];
#pragma unroll
  for (int i = 0; i < 8; ++i) { sqa[i] = 0.f; sqb[i] = 0.f; }
  const int q = tid & 15, r0 = tid >> 4;

  for (int ks = 0; ks < Kdim; ks += 64) {
    __syncthreads();
#pragma unroll
    for (int i = 0; i < 8; ++i) {
      const int r = r0 + 16 * i;
      f32x4 va = *(const f32x4*)(X  + (size_t)(bm0 + r) * Kdim + ks + q * 4);
      f32x4 vb = *(const f32x4*)(Cc + (size_t)(bn0 + r) * Kdim + ks + q * 4);
      sqa[i] = fmaf(va[0], va[0], fmaf(va[1], va[1], fmaf(va[2], va[2], fmaf(va[3], va[3], sqa[i]))));
      sqb[i] = fmaf(vb[0], vb[0], fmaf(vb[1], vb[1], fmaf(vb[2], vb[2], fmaf(vb[3], vb[3], sqb[i]))));
      const int slot = q ^ ((r & 7) << 1);
      As[r * 16 + slot] = pack4(va);
      Bs[r * 16 + slot] = pack4(vb);
    }
    __syncthreads();
#pragma unroll
    for (int kk = 0; kk < 64; kk += 32) {
      bf16x8 af[4], bf[4];
      const int kslot = (kk >> 2) + ((lane >> 4) << 1);
#pragma unroll
      for (int mi = 0; mi < 4; ++mi) {
        const int r = wm + mi * 16 + (lane & 15);
        af[mi] = *(const bf16x8*)&As[r * 16 + (kslot ^ ((r & 7) << 1))];
      }
#pragma unroll
      for (int ni = 0; ni < 4; ++ni) {
        const int r = wn + ni * 16 + (lane & 15);
        bf[ni] = *(const bf16x8*)&Bs[r * 16 + (kslot ^ ((r & 7) << 1))];
      }
#pragma unroll
      for (int mi = 0; mi < 4; ++mi)
#pragma unroll
        for (int ni = 0; ni < 4; ++ni)
          acc[mi][ni] = __builtin_amdgcn_mfma_f32_16x16x32_bf16(af[mi], bf[ni], acc[mi][ni], 0, 0, 0);
    }
  }
#pragma unroll
  for (int i = 0; i < 8; ++i) {
    float v = sqa[i];
    v += __shfl_xor(v, 1); v += __shfl_xor(v, 2); v += __shfl_xor(v, 4); v += __shfl_xor(v, 8);
    float w = sqb[i];
    w += __shfl_xor(w, 1); w += __shfl_xor(w, 2); w += __shfl_xor(w, 4); w += __shfl_xor(w, 8);
    if ((lane & 15) == 0) { x2s[r0 + 16 * i] = v; c2s[r0 + 16 * i] = w; }
  }
  __syncthreads();
  const int colb = lane & 15, rowb = (lane >> 4) << 2;
#pragma unroll
  for (int mi = 0; mi < 4; ++mi) {
    const int rL = wm + mi * 16 + rowb;
    const float x0 = x2s[rL + 0], x1 = x2s[rL + 1], x2v = x2s[rL + 2], x3 = x2s[rL + 3];
#pragma unroll
    for (int ni = 0; ni < 4; ++ni) {
      const int cL = wn + ni * 16 + colb;
      const float cv = c2s[cL];
      f32x4 a = acc[mi][ni];
      float pm[4], ps[4];
      pm[0] = __expf(-0.5f * (x0  + cv - 2.f * a[0]));
      pm[1] = __expf(-0.5f * (x1  + cv - 2.f * a[1]));
      pm[2] = __expf(-0.5f * (x2v + cv - 2.f * a[2]));
      pm[3] = __expf(-0.5f * (x3  + cv - 2.f * a[3]));
#pragma unroll
      for (int j = 0; j < 4; ++j) ps[j] = pm[j];
#pragma unroll
      for (int s = 1; s < 8; s <<= 1) {
#pragma unroll
        for (int j = 0; j < 4; ++j) {
          pm[j] = fmaxf(pm[j], __shfl_xor(pm[j], s));
          ps[j] += __shfl_xor(ps[j], s);
        }
      }
      if ((lane & 7) == 0) {
        const int o = (bn0 + cL) >> 3;
#pragma unroll
        for (int j = 0; j < 4; ++j)
          Out[(size_t)(bm0 + rL + j) * OUTC + o] = (pm[j] * 9.f - ps[j]) * 0.125f;
      }
    }
  }
}

// ---------------------------------------------------------------------------
extern "C" void kernel_launch(void* const* d_in, const int* in_sizes, int n_in,
                              void* d_out, int out_size, void* d_ws, size_t ws_size,
                              hipStream_t stream) {
  const float* X  = (const float*)d_in[0];
  const float* Cc = (const float*)d_in[1];
  float* Out = (float*)d_out;

  if (ws_size >= WS_NEED) {
    ushort* Xb = (ushort*)((char*)d_ws + WS_XB);
    ushort* Cb = (ushort*)((char*)d_ws + WS_CB);
    float*  x2 = (float*)((char*)d_ws + WS_X2);
    float*  c2 = (float*)((char*)d_ws + WS_C2);
    convert_norm<<<dim3((Mdim + Ndim) / 4), dim3(256), 0, stream>>>(X, Cc, Xb, Cb, x2, c2);
    (void)hipFuncSetAttribute((const void*)pnn_gemm8,
                              hipFuncAttributeMaxDynamicSharedMemorySize, 131072);
    pnn_gemm8<<<dim3(256), dim3(512), 131072, stream>>>(Xb, Cb, x2, c2, Out);
  } else {
    dim3 grid(Ndim / 128, Mdim / 128);
    pnn_fused<<<grid, dim3(256), 0, stream>>>(X, Cc, Out);
  }
}